// Round 4
// baseline (143.045 us; speedup 1.0000x reference)
//
#include <hip/hip_runtime.h>
#include <hip/hip_bf16.h>
#include <math.h>

typedef _Float16 f16x8 __attribute__((ext_vector_type(8)));
typedef _Float16 f16x4 __attribute__((ext_vector_type(4)));
typedef float    f32x4 __attribute__((ext_vector_type(4)));

#define IMG   400
#define NPIX  160000
#define NKT1  18                  // K1 padded: (c,ki,kj)->(3,12,16) = 576
#define W1P   (NKT1*8*64*8)       // 73728 f16
#define W2P   (4*4*64*8)          // 8192
#define W3P   (2*64*8)            // 1024
#define H1S   136                 // h1 stride (128+8)
#define H2S   72                  // h2 stride (64+8)
#define XSR   27                  // halo rows staged (16 tile + 10 halo + 1 phantom)
#define XSS   34                  // slots per row per phase
#define XPE   (3*XSR*XSS)         // 2754 f16 per phase

// ---------------------------------------------------------------------------
// Pack fp32 weights into fp16 MFMA A-fragment order (A[m=lane&15][k=q*8+j]).
// W1 uses permuted K: k' = (c*12 + ki)*16 + kj (ki 11->12, kj 11->16, zeros).
// ---------------------------------------------------------------------------
__global__ void pack_weights(const float* __restrict__ W1,
                             const float* __restrict__ W2,
                             const float* __restrict__ W3,
                             _Float16* __restrict__ ws)
{
    int i = blockIdx.x * blockDim.x + threadIdx.x;
    if (i < 576 * 128) {                      // W1 region
        int kp = i >> 7, n = i & 127;
        int kt = kp >> 5, kl = kp & 31, q = kl >> 3, j = kl & 7;
        int pair = kp >> 4, kj = kp & 15;
        int c = pair / 12, ki = pair % 12;
        int mt = n >> 4, n15 = n & 15;
        int lane = q * 16 + n15;
        float v = (ki < 11 && kj < 11) ? W1[(c * 121 + ki * 11 + kj) * 128 + n] : 0.0f;
        ws[((kt * 8 + mt) * 64 + lane) * 8 + j] = (_Float16)v;
    } else if (i < 576 * 128 + 128 * 64) {    // W2 region
        int e = i - 576 * 128;
        int kp = e >> 6, n = e & 63;
        int kt = kp >> 5, kl = kp & 31, q = kl >> 3, j = kl & 7;
        int mt = n >> 4, n15 = n & 15;
        int lane = q * 16 + n15;
        ws[W1P + ((kt * 4 + mt) * 64 + lane) * 8 + j] = (_Float16)W2[kp * 64 + n];
    } else if (i < 576 * 128 + 128 * 64 + 64 * 16) {  // W3 region (N pad 8->16)
        int e = i - 576 * 128 - 128 * 64;
        int kp = e >> 4, n = e & 15;
        int kt = kp >> 5, kl = kp & 31, q = kl >> 3, j = kl & 7;
        int lane = q * 16 + n;
        float v = (n < 8) ? W3[kp * 8 + n] : 0.0f;
        ws[W1P + W2P + (kt * 64 + lane) * 8 + j] = (_Float16)v;
    }
}

// ---------------------------------------------------------------------------
// Fused conv-MLP. Block = 256 thr (4 waves) = 16x16 pixel tile; wave = 4 image
// rows x 16 cols (4 n-tiles of 16 pixels). A = weights (m = out-ch),
// B = pixels (n = pixel). Each weight A-frag load feeds 4 MFMAs.
// Layouts: A[m=lane&15][k=q*8+j], B[k=q*8+j][n=lane&15], D[m=q*4+r][n=lane&15].
// ---------------------------------------------------------------------------
__global__ __launch_bounds__(256, 2) void fused_unfold_mlp(
    const float* __restrict__ x,
    const float* __restrict__ b1,
    const float* __restrict__ b2,
    const float* __restrict__ b3,
    const _Float16* __restrict__ wpack,
    float* __restrict__ out)
{
    __shared__ __align__(16) _Float16 xs[2 * XPE];        // 11016 B
    __shared__ __align__(16) _Float16 hb[4 * 64 * H1S];   // 69632 B

    const int tid  = threadIdx.x;
    const int wave = tid >> 6;
    const int lane = tid & 63;
    const int q    = lane >> 4;
    const int n15  = lane & 15;
    const int bx   = blockIdx.x;   // 0..24 (col tiles)
    const int by   = blockIdx.y;   // 0..24 (row tiles)

    // ---- stage x halo: rows gy in [by*16-5, by*16+21], cols gx in [bx*16-6, +28]
    // P0 slot s holds col s-5; P1 slot s holds col s-6 (dword-alignment phases).
    for (int w = tid; w < 3 * XSR * 35; w += 256) {
        int col = w % 35;
        int rc  = w / 35;
        int row = rc % XSR, c = rc / XSR;
        int gy = by * 16 + row - 5;
        int gx = bx * 16 + col - 6;
        float v = 0.0f;
        if ((unsigned)gy < (unsigned)IMG && (unsigned)gx < (unsigned)IMG)
            v = x[c * NPIX + gy * IMG + gx];
        _Float16 hv = (_Float16)v;
        int base = (c * XSR + row) * XSS;
        if (col >= 1)  xs[base + col - 1] = hv;        // P0
        if (col <= 33) xs[XPE + base + col] = hv;      // P1
    }
    __syncthreads();

    const _Float16* w1p = wpack;
    const _Float16* w2p = wpack + W1P;
    const _Float16* w3p = wpack + W1P + W2P;
    _Float16* hw = &hb[wave * 64 * H1S];     // wave-private h staging

    // B-fragment base dword index into xs (per n-tile t = image row wave*4+t)
    const uint32_t* xsd = (const uint32_t*)xs;
    const int h = q >> 1;                              // ki row-pair select
    const int u = n15 + (n15 & 1) + ((q & 1) << 3);    // aligned slot start
    const int bdw0 = (n15 & 1) * (XPE / 2) + (u >> 1);
    int bdwt[4];
#pragma unroll
    for (int t = 0; t < 4; ++t)
        bdwt[t] = bdw0 + (wave * 4 + t + h) * 17;

    // ---------------- layer 1: 128ch x 576K x 64pix ----------------
    f32x4 acc1[4][8];
#pragma unroll
    for (int t = 0; t < 4; ++t)
#pragma unroll
        for (int mt = 0; mt < 8; ++mt)
            acc1[t][mt] = (f32x4){0.f, 0.f, 0.f, 0.f};

#pragma unroll
    for (int kt = 0; kt < NKT1; ++kt) {
        const int rim = ((kt / 6) * XSR + 2 * (kt % 6)) * 17;  // row imm (dwords)
        f16x8 bf[4];
#pragma unroll
        for (int t = 0; t < 4; ++t) {
            union { uint32_t u[4]; f16x8 f; } cv;
#pragma unroll
            for (int m = 0; m < 4; ++m)
                cv.u[m] = xsd[bdwt[t] + rim + m];
            bf[t] = cv.f;
        }
#pragma unroll
        for (int mt = 0; mt < 8; ++mt) {
            f16x8 af = *(const f16x8*)(w1p + ((kt * 8 + mt) * 64 + lane) * 8);
#pragma unroll
            for (int t = 0; t < 4; ++t)
                acc1[t][mt] = __builtin_amdgcn_mfma_f32_16x16x32_f16(af, bf[t], acc1[t][mt], 0, 0, 0);
        }
    }

    // epilogue 1: +b1, leaky, h1[pix][ch] fp16 (4 contig ch/lane -> b64 writes)
#pragma unroll
    for (int mt = 0; mt < 8; ++mt) {
        float4 bb = *(const float4*)(b1 + mt * 16 + q * 4);
#pragma unroll
        for (int t = 0; t < 4; ++t) {
            f16x4 hv;
#pragma unroll
            for (int r = 0; r < 4; ++r) {
                float v = acc1[t][mt][r] + ((const float*)&bb)[r];
                v = fmaxf(v, 0.01f * v);
                hv[r] = (_Float16)v;
            }
            *(f16x4*)(hw + (t * 16 + n15) * H1S + mt * 16 + q * 4) = hv;
        }
    }
    // wave-private LDS, in-order DS per wave: no barrier needed

    // ---------------- layer 2: 64ch x 128K x 64pix ----------------
    f32x4 acc2[4][4];
#pragma unroll
    for (int t = 0; t < 4; ++t)
#pragma unroll
        for (int mt = 0; mt < 4; ++mt)
            acc2[t][mt] = (f32x4){0.f, 0.f, 0.f, 0.f};

#pragma unroll
    for (int kt = 0; kt < 4; ++kt) {
        f16x8 bf[4];
#pragma unroll
        for (int t = 0; t < 4; ++t)
            bf[t] = *(const f16x8*)(hw + (t * 16 + n15) * H1S + kt * 32 + q * 8);
#pragma unroll
        for (int mt = 0; mt < 4; ++mt) {
            f16x8 af = *(const f16x8*)(w2p + ((kt * 4 + mt) * 64 + lane) * 8);
#pragma unroll
            for (int t = 0; t < 4; ++t)
                acc2[t][mt] = __builtin_amdgcn_mfma_f32_16x16x32_f16(af, bf[t], acc2[t][mt], 0, 0, 0);
        }
    }

    // epilogue 2: +b2, leaky, h2[pix][ch]
#pragma unroll
    for (int mt = 0; mt < 4; ++mt) {
        float4 bb = *(const float4*)(b2 + mt * 16 + q * 4);
#pragma unroll
        for (int t = 0; t < 4; ++t) {
            f16x4 hv;
#pragma unroll
            for (int r = 0; r < 4; ++r) {
                float v = acc2[t][mt][r] + ((const float*)&bb)[r];
                v = fmaxf(v, 0.01f * v);
                hv[r] = (_Float16)v;
            }
            *(f16x4*)(hw + (t * 16 + n15) * H2S + mt * 16 + q * 4) = hv;
        }
    }

    // ---------------- layer 3: 8ch(pad16) x 64K x 64pix ----------------
    f32x4 acc3[4];
#pragma unroll
    for (int t = 0; t < 4; ++t)
        acc3[t] = (f32x4){0.f, 0.f, 0.f, 0.f};
#pragma unroll
    for (int kt = 0; kt < 2; ++kt) {
        f16x8 af = *(const f16x8*)(w3p + (kt * 64 + lane) * 8);
#pragma unroll
        for (int t = 0; t < 4; ++t) {
            f16x8 bf = *(const f16x8*)(hw + (t * 16 + n15) * H2S + kt * 32 + q * 8);
            acc3[t] = __builtin_amdgcn_mfma_f32_16x16x32_f16(af, bf, acc3[t], 0, 0, 0);
        }
    }

    // epilogue 3: +b3, L2-normalize over 8 ch (ch = q*4+r; q>=2 zero pad)
    float4 bb3 = make_float4(0.f, 0.f, 0.f, 0.f);
    if (q < 2) bb3 = *(const float4*)(b3 + q * 4);
#pragma unroll
    for (int t = 0; t < 4; ++t) {
        float v0 = acc3[t][0] + bb3.x;
        float v1 = acc3[t][1] + bb3.y;
        float v2 = acc3[t][2] + bb3.z;
        float v3 = acc3[t][3] + bb3.w;
        float s = v0 * v0 + v1 * v1 + v2 * v2 + v3 * v3;
        s += __shfl_xor(s, 16);
        s += __shfl_xor(s, 32);
        float inv = 1.0f / fmaxf(sqrtf(s), 1e-12f);
        if (q < 2) {
            int p = (by * 16 + wave * 4 + t) * IMG + bx * 16 + n15;
            float4 o = make_float4(v0 * inv, v1 * inv, v2 * inv, v3 * inv);
            *(float4*)(out + p * 8 + q * 4) = o;
        }
    }
}

extern "C" void kernel_launch(void* const* d_in, const int* in_sizes, int n_in,
                              void* d_out, int out_size, void* d_ws, size_t ws_size,
                              hipStream_t stream) {
    const float* x  = (const float*)d_in[0];
    const float* W1 = (const float*)d_in[1];
    const float* b1 = (const float*)d_in[2];
    const float* W2 = (const float*)d_in[3];
    const float* b2 = (const float*)d_in[4];
    const float* W3 = (const float*)d_in[5];
    const float* b3 = (const float*)d_in[6];
    float* out = (float*)d_out;
    _Float16* ws = (_Float16*)d_ws;   // needs 165888 B

    pack_weights<<<dim3(324), dim3(256), 0, stream>>>(W1, W2, W3, ws);
    fused_unfold_mlp<<<dim3(25, 25), dim3(256), 0, stream>>>(x, b1, b2, b3, ws, out);
}

// Round 5
// 107.548 us; speedup vs baseline: 1.3301x; 1.3301x over previous
//
#include <hip/hip_runtime.h>
#include <hip/hip_bf16.h>
#include <math.h>

typedef _Float16 f16x8 __attribute__((ext_vector_type(8)));
typedef _Float16 f16x4 __attribute__((ext_vector_type(4)));
typedef float    f32x4 __attribute__((ext_vector_type(4)));

#define IMG   400
#define NPIX  160000
#define NKT1  18                  // K1 padded: (c,ki,kj)->(3,12,16) = 576
#define W1P   (NKT1*8*64*8)       // 73728 f16 (18 chunks x 4096)
#define W2P   (4*4*64*8)          // 8192
#define W3P   (2*64*8)            // 1024
#define H1S   136                 // h1 stride (128+8)
#define H2S   72                  // h2 stride (64+8)
#define XPH   1938                // x-tile elems per phase: 3c * 19rows * 34slots

// async global->LDS, 16B per lane; LDS dest = wave-uniform base + lane*16
__device__ __forceinline__ void async_cp16(const _Float16* g, _Float16* l) {
    __builtin_amdgcn_global_load_lds(
        (const __attribute__((address_space(1))) uint32_t*)g,
        (__attribute__((address_space(3))) uint32_t*)l, 16, 0, 0);
}

// ---------------------------------------------------------------------------
// Pack fp32 weights into fp16 MFMA A-fragment order (A[m=lane&15][k=q*8+j]).
// W1 permuted K: k' = (c*12 + ki)*16 + kj (ki 11->12, kj 11->16, zero pads).
// ---------------------------------------------------------------------------
__global__ void pack_weights(const float* __restrict__ W1,
                             const float* __restrict__ W2,
                             const float* __restrict__ W3,
                             _Float16* __restrict__ ws)
{
    int i = blockIdx.x * blockDim.x + threadIdx.x;
    if (i < 576 * 128) {                      // W1 region
        int kp = i >> 7, n = i & 127;
        int kt = kp >> 5, kl = kp & 31, q = kl >> 3, j = kl & 7;
        int pair = kp >> 4, kj = kp & 15;
        int c = pair / 12, ki = pair % 12;
        int mt = n >> 4, n15 = n & 15;
        int lane = q * 16 + n15;
        float v = (ki < 11 && kj < 11) ? W1[(c * 121 + ki * 11 + kj) * 128 + n] : 0.0f;
        ws[((kt * 8 + mt) * 64 + lane) * 8 + j] = (_Float16)v;
    } else if (i < 576 * 128 + 128 * 64) {    // W2 region
        int e = i - 576 * 128;
        int kp = e >> 6, n = e & 63;
        int kt = kp >> 5, kl = kp & 31, q = kl >> 3, j = kl & 7;
        int mt = n >> 4, n15 = n & 15;
        int lane = q * 16 + n15;
        ws[W1P + ((kt * 4 + mt) * 64 + lane) * 8 + j] = (_Float16)W2[kp * 64 + n];
    } else if (i < 576 * 128 + 128 * 64 + 64 * 16) {  // W3 region (N pad 8->16)
        int e = i - 576 * 128 - 128 * 64;
        int kp = e >> 4, n = e & 15;
        int kt = kp >> 5, kl = kp & 31, q = kl >> 3, j = kl & 7;
        int lane = q * 16 + n;
        float v = (n < 8) ? W3[kp * 8 + n] : 0.0f;
        ws[W1P + W2P + (kt * 64 + lane) * 8 + j] = (_Float16)v;
    }
}

// ---------------------------------------------------------------------------
// Fused conv-MLP. Block = 256 thr (4 waves) = 16x8 pixel tile; wave = 2 image
// rows x 16 cols. A = weights (m = out-ch), B = pixels (n = pixel).
// W1 double-buffered through LDS via global_load_lds; kt start staggered per
// block to parallelize L2 warm-up across chunks (breaks the cold-L2 convoy).
// Layouts: A[m=lane&15][k=q*8+j], B[k=q*8+j][n=lane&15], D[m=q*4+r][n=lane&15].
// ---------------------------------------------------------------------------
__global__ __launch_bounds__(256, 2) void fused_unfold_mlp(
    const float* __restrict__ x,
    const float* __restrict__ b1,
    const float* __restrict__ b2,
    const float* __restrict__ b3,
    const _Float16* __restrict__ wpack,
    float* __restrict__ out)
{
    __shared__ __align__(16) _Float16 xs[2 * XPH];        // 7752 B
    __shared__ __align__(16) _Float16 hb[4 * 32 * H1S];   // 34816 B
    __shared__ __align__(16) _Float16 w1s[2 * 4096];      // 16384 B dbuf

    const int tid  = threadIdx.x;
    const int wave = tid >> 6;
    const int lane = tid & 63;
    const int q    = lane >> 4;
    const int n15  = lane & 15;
    const int bx   = blockIdx.x;   // 0..24
    const int by   = blockIdx.y;   // 0..49

    const _Float16* w1p = wpack;
    const _Float16* w2p = wpack + W1P;
    const _Float16* w3p = wpack + W1P + W2P;

    const int kt0 = (bx + by * 25) % NKT1;   // per-block chunk stagger

    // ---- issue prefetch of W1 chunk kt0 into buf0 (hides under x staging)
    {
        int seg = wave * 2;
        async_cp16(w1p + kt0 * 4096 + seg * 512 + lane * 8, &w1s[seg * 512]);
        async_cp16(w1p + kt0 * 4096 + (seg + 1) * 512 + lane * 8, &w1s[(seg + 1) * 512]);
    }

    // ---- stage x halo: rows gy in [by*8-5, by*8+13], cols gx in [bx*16-6,+28]
    // P0 slot s holds col s-5; P1 slot s holds col s-6 (dword-alignment phases)
    for (int w = tid; w < 3 * 19 * 35; w += 256) {
        int col = w % 35;
        int rc  = w / 35;
        int row = rc % 19, c = rc / 19;
        int gy = by * 8 + row - 5;
        int gx = bx * 16 + col - 6;
        float v = 0.0f;
        if ((unsigned)gy < (unsigned)IMG && (unsigned)gx < (unsigned)IMG)
            v = x[c * NPIX + gy * IMG + gx];
        _Float16 hv = (_Float16)v;
        int base = (c * 19 + row) * 34;
        if (col >= 1)  xs[base + col - 1] = hv;        // P0
        if (col <= 33) xs[XPH + base + col] = hv;      // P1
    }
    __syncthreads();   // drains staging stores AND the chunk-kt0 prefetch

    _Float16* hw = &hb[wave * 32 * H1S];     // wave-private h staging

    // B-fragment base dword index into xs (per n-tile t = image row wave*2+t)
    const uint32_t* xsd = (const uint32_t*)xs;
    const int h = q >> 1;
    const int u = n15 + (n15 & 1) + ((q & 1) << 3);
    const int bdw0 = (n15 & 1) * (XPH / 2) + (u >> 1);
    int bdwt[2];
#pragma unroll
    for (int t = 0; t < 2; ++t)
        bdwt[t] = bdw0 + (wave * 2 + t + h) * 17;

    // ---------------- layer 1: 128ch x 576K x 32pix ----------------
    f32x4 acc1[2][8];
#pragma unroll
    for (int t = 0; t < 2; ++t)
#pragma unroll
        for (int mt = 0; mt < 8; ++mt)
            acc1[t][mt] = (f32x4){0.f, 0.f, 0.f, 0.f};

    int kt = kt0;
    for (int kk = 0; kk < NKT1; ++kk) {
        if (kk) __syncthreads();   // prev prefetch landed; cur buf safe to read
        const int buf  = kk & 1;
        const int nbuf = buf ^ 1;
        const int ktn  = (kt + 1 == NKT1) ? 0 : kt + 1;
        if (kk < NKT1 - 1) {       // prefetch next chunk into other buffer
            int seg = wave * 2;
            async_cp16(w1p + ktn * 4096 + seg * 512 + lane * 8,
                       &w1s[nbuf * 4096 + seg * 512]);
            async_cp16(w1p + ktn * 4096 + (seg + 1) * 512 + lane * 8,
                       &w1s[nbuf * 4096 + (seg + 1) * 512]);
        }

        const int d6  = (kt >= 12) ? 2 : (kt >= 6 ? 1 : 0);
        const int m6  = kt - d6 * 6;
        const int rim = (d6 * 19 + 2 * m6) * 17;   // xs row offset (dwords)

        f16x8 bf[2];
#pragma unroll
        for (int t = 0; t < 2; ++t) {
            union { uint32_t u[4]; f16x8 f; } cv;
#pragma unroll
            for (int m = 0; m < 4; ++m)
                cv.u[m] = xsd[bdwt[t] + rim + m];
            bf[t] = cv.f;
        }
        const _Float16* wb = &w1s[buf * 4096];
#pragma unroll
        for (int mt = 0; mt < 8; ++mt) {
            f16x8 af = *(const f16x8*)(wb + (mt * 64 + lane) * 8);
            acc1[0][mt] = __builtin_amdgcn_mfma_f32_16x16x32_f16(af, bf[0], acc1[0][mt], 0, 0, 0);
            acc1[1][mt] = __builtin_amdgcn_mfma_f32_16x16x32_f16(af, bf[1], acc1[1][mt], 0, 0, 0);
        }
        kt = ktn;
    }

    // ---- preload W2/W3 fragments into registers (one latency exposure)
    f16x8 af2[4][4];
#pragma unroll
    for (int k2 = 0; k2 < 4; ++k2)
#pragma unroll
        for (int mt = 0; mt < 4; ++mt)
            af2[k2][mt] = *(const f16x8*)(w2p + ((k2 * 4 + mt) * 64 + lane) * 8);
    f16x8 af3[2];
#pragma unroll
    for (int k3 = 0; k3 < 2; ++k3)
        af3[k3] = *(const f16x8*)(w3p + (k3 * 64 + lane) * 8);

    // epilogue 1: +b1, leaky, h1[pix][ch] fp16 (4 contig ch/lane -> b64 writes)
#pragma unroll
    for (int mt = 0; mt < 8; ++mt) {
        float4 bb = *(const float4*)(b1 + mt * 16 + q * 4);
#pragma unroll
        for (int t = 0; t < 2; ++t) {
            f16x4 hv;
#pragma unroll
            for (int r = 0; r < 4; ++r) {
                float v = acc1[t][mt][r] + ((const float*)&bb)[r];
                v = fmaxf(v, 0.01f * v);
                hv[r] = (_Float16)v;
            }
            *(f16x4*)(hw + (t * 16 + n15) * H1S + mt * 16 + q * 4) = hv;
        }
    }
    // wave-private LDS, in-order DS per wave: no barrier needed

    // ---------------- layer 2: 64ch x 128K x 32pix ----------------
    f32x4 acc2[2][4];
#pragma unroll
    for (int t = 0; t < 2; ++t)
#pragma unroll
        for (int mt = 0; mt < 4; ++mt)
            acc2[t][mt] = (f32x4){0.f, 0.f, 0.f, 0.f};

#pragma unroll
    for (int k2 = 0; k2 < 4; ++k2) {
        f16x8 bf[2];
#pragma unroll
        for (int t = 0; t < 2; ++t)
            bf[t] = *(const f16x8*)(hw + (t * 16 + n15) * H1S + k2 * 32 + q * 8);
#pragma unroll
        for (int mt = 0; mt < 4; ++mt) {
            acc2[0][mt] = __builtin_amdgcn_mfma_f32_16x16x32_f16(af2[k2][mt], bf[0], acc2[0][mt], 0, 0, 0);
            acc2[1][mt] = __builtin_amdgcn_mfma_f32_16x16x32_f16(af2[k2][mt], bf[1], acc2[1][mt], 0, 0, 0);
        }
    }

    // epilogue 2: +b2, leaky, h2[pix][ch]
#pragma unroll
    for (int mt = 0; mt < 4; ++mt) {
        float4 bb = *(const float4*)(b2 + mt * 16 + q * 4);
#pragma unroll
        for (int t = 0; t < 2; ++t) {
            f16x4 hv;
#pragma unroll
            for (int r = 0; r < 4; ++r) {
                float v = acc2[t][mt][r] + ((const float*)&bb)[r];
                v = fmaxf(v, 0.01f * v);
                hv[r] = (_Float16)v;
            }
            *(f16x4*)(hw + (t * 16 + n15) * H2S + mt * 16 + q * 4) = hv;
        }
    }

    // ---------------- layer 3: 8ch(pad16) x 64K x 32pix ----------------
    f32x4 acc3[2];
    acc3[0] = (f32x4){0.f, 0.f, 0.f, 0.f};
    acc3[1] = (f32x4){0.f, 0.f, 0.f, 0.f};
#pragma unroll
    for (int k3 = 0; k3 < 2; ++k3) {
#pragma unroll
        for (int t = 0; t < 2; ++t) {
            f16x8 bf = *(const f16x8*)(hw + (t * 16 + n15) * H2S + k3 * 32 + q * 8);
            acc3[t] = __builtin_amdgcn_mfma_f32_16x16x32_f16(af3[k3], bf, acc3[t], 0, 0, 0);
        }
    }

    // epilogue 3: +b3, L2-normalize over 8 ch (ch = q*4+r; q>=2 zero pad)
    float4 bb3 = make_float4(0.f, 0.f, 0.f, 0.f);
    if (q < 2) bb3 = *(const float4*)(b3 + q * 4);
#pragma unroll
    for (int t = 0; t < 2; ++t) {
        float v0 = acc3[t][0] + bb3.x;
        float v1 = acc3[t][1] + bb3.y;
        float v2 = acc3[t][2] + bb3.z;
        float v3 = acc3[t][3] + bb3.w;
        float s = v0 * v0 + v1 * v1 + v2 * v2 + v3 * v3;
        s += __shfl_xor(s, 16);
        s += __shfl_xor(s, 32);
        float inv = 1.0f / fmaxf(sqrtf(s), 1e-12f);
        if (q < 2) {
            int p = (by * 8 + wave * 2 + t) * IMG + bx * 16 + n15;
            float4 o = make_float4(v0 * inv, v1 * inv, v2 * inv, v3 * inv);
            *(float4*)(out + p * 8 + q * 4) = o;
        }
    }
}

extern "C" void kernel_launch(void* const* d_in, const int* in_sizes, int n_in,
                              void* d_out, int out_size, void* d_ws, size_t ws_size,
                              hipStream_t stream) {
    const float* x  = (const float*)d_in[0];
    const float* W1 = (const float*)d_in[1];
    const float* b1 = (const float*)d_in[2];
    const float* W2 = (const float*)d_in[3];
    const float* b2 = (const float*)d_in[4];
    const float* W3 = (const float*)d_in[5];
    const float* b3 = (const float*)d_in[6];
    float* out = (float*)d_out;
    _Float16* ws = (_Float16*)d_ws;   // needs 165888 B

    pack_weights<<<dim3(324), dim3(256), 0, stream>>>(W1, W2, W3, ws);
    fused_unfold_mlp<<<dim3(25, 50), dim3(256), 0, stream>>>(x, b1, b2, b3, ws, out);
}

// Round 7
// 97.795 us; speedup vs baseline: 1.4627x; 1.0997x over previous
//
#include <hip/hip_runtime.h>
#include <hip/hip_bf16.h>
#include <math.h>

typedef _Float16 f16x8 __attribute__((ext_vector_type(8)));
typedef _Float16 f16x4 __attribute__((ext_vector_type(4)));
typedef float    f32x4 __attribute__((ext_vector_type(4)));

#define IMG   400
#define NPIX  160000
#define NKT1  18                  // K1 padded: (c,ki,kj)->(3,12,16) = 576
#define W1P   (NKT1*8*64*8)       // 73728 f16 (18 chunks x 4096)
#define W2P   (4*4*64*8)          // 8192
#define W3P   (2*64*8)            // 1024
#define HSS   40                  // h-slice row stride (32 ch + 8 pad)
#define XPH   1938                // x-tile elems per phase: 3c * 19rows * 34slots

// async global->LDS, 16B per lane; LDS dest = wave-uniform base + lane*16
__device__ __forceinline__ void async_cp16(const _Float16* g, _Float16* l) {
    __builtin_amdgcn_global_load_lds(
        (const __attribute__((address_space(1))) uint32_t*)g,
        (__attribute__((address_space(3))) uint32_t*)l, 16, 0, 0);
}

// ---------------------------------------------------------------------------
// Pack fp32 weights into fp16 MFMA A-fragment order (A[m=lane&15][k=q*8+j]).
// W1 permuted K: k' = (c*12 + ki)*16 + kj (ki 11->12, kj 11->16, zero pads).
// ---------------------------------------------------------------------------
__global__ void pack_weights(const float* __restrict__ W1,
                             const float* __restrict__ W2,
                             const float* __restrict__ W3,
                             _Float16* __restrict__ ws)
{
    int i = blockIdx.x * blockDim.x + threadIdx.x;
    if (i < 576 * 128) {                      // W1 region
        int kp = i >> 7, n = i & 127;
        int kt = kp >> 5, kl = kp & 31, q = kl >> 3, j = kl & 7;
        int pair = kp >> 4, kj = kp & 15;
        int c = pair / 12, ki = pair % 12;
        int mt = n >> 4, n15 = n & 15;
        int lane = q * 16 + n15;
        float v = (ki < 11 && kj < 11) ? W1[(c * 121 + ki * 11 + kj) * 128 + n] : 0.0f;
        ws[((kt * 8 + mt) * 64 + lane) * 8 + j] = (_Float16)v;
    } else if (i < 576 * 128 + 128 * 64) {    // W2 region
        int e = i - 576 * 128;
        int kp = e >> 6, n = e & 63;
        int kt = kp >> 5, kl = kp & 31, q = kl >> 3, j = kl & 7;
        int mt = n >> 4, n15 = n & 15;
        int lane = q * 16 + n15;
        ws[W1P + ((kt * 4 + mt) * 64 + lane) * 8 + j] = (_Float16)W2[kp * 64 + n];
    } else if (i < 576 * 128 + 128 * 64 + 64 * 16) {  // W3 region (N pad 8->16)
        int e = i - 576 * 128 - 128 * 64;
        int kp = e >> 4, n = e & 15;
        int kt = kp >> 5, kl = kp & 31, q = kl >> 3, j = kl & 7;
        int lane = q * 16 + n;
        float v = (n < 8) ? W3[kp * 8 + n] : 0.0f;
        ws[W1P + W2P + (kt * 64 + lane) * 8 + j] = (_Float16)v;
    }
}

// ---------------------------------------------------------------------------
// Fused conv-MLP. Block = 256 thr (4 waves) = 16x8 pixel tile; wave = 2 image
// rows x 16 cols. A = weights (m = out-ch), B = pixels (n = pixel).
// W1 double-buffered via global_load_lds (kt staggered per block). W2 staged
// in two 8 KB halves: first half into the idle nbuf half at the last kt,
// second half after a barrier retires the last chunk's reads (R6 bug: the
// single-shot 16 KB staging clobbered the live W1 buffer). h1/h2 flow through
// a 2.5 KB wave-private slice (32 ch at a time, interleaved with layer-2/3
// MFMAs; in-order DS per wave -> no barriers). LDS 34.4 KB -> 4 blocks/CU.
// Layouts: A[m=lane&15][k=q*8+j], B[k=q*8+j][n=lane&15], D[m=q*4+r][n=lane&15].
// ---------------------------------------------------------------------------
__global__ __launch_bounds__(256, 4) void fused_unfold_mlp(
    const float* __restrict__ x,
    const float* __restrict__ b1,
    const float* __restrict__ b2,
    const float* __restrict__ b3,
    const _Float16* __restrict__ wpack,
    float* __restrict__ out)
{
    __shared__ __align__(16) _Float16 xs[2 * XPH];        // 7752 B
    __shared__ __align__(16) _Float16 w1s[2 * 4096];      // 16384 B dbuf
    __shared__ __align__(16) _Float16 hs[4][32 * HSS];    // 10240 B slices

    const int tid  = threadIdx.x;
    const int wave = tid >> 6;
    const int lane = tid & 63;
    const int q    = lane >> 4;
    const int n15  = lane & 15;
    const int bx   = blockIdx.x;   // 0..24
    const int by   = blockIdx.y;   // 0..49

    const _Float16* w1p = wpack;
    const _Float16* w2p = wpack + W1P;
    const _Float16* w3p = wpack + W1P + W2P;

    const int kt0 = (bx + by * 25) % NKT1;   // per-block chunk stagger

    // ---- issue prefetch of W1 chunk kt0 into buf0 (hides under x staging)
    {
        int seg = wave * 2;
        async_cp16(w1p + kt0 * 4096 + seg * 512 + lane * 8, &w1s[seg * 512]);
        async_cp16(w1p + kt0 * 4096 + (seg + 1) * 512 + lane * 8, &w1s[(seg + 1) * 512]);
    }

    // ---- stage x halo: rows gy in [by*8-5, by*8+13], cols gx in [bx*16-6,+28]
    // P0 slot s holds col s-5; P1 slot s holds col s-6 (dword-alignment phases)
    for (int w = tid; w < 3 * 19 * 35; w += 256) {
        int col = w % 35;
        int rc  = w / 35;
        int row = rc % 19, c = rc / 19;
        int gy = by * 8 + row - 5;
        int gx = bx * 16 + col - 6;
        float v = 0.0f;
        if ((unsigned)gy < (unsigned)IMG && (unsigned)gx < (unsigned)IMG)
            v = x[c * NPIX + gy * IMG + gx];
        _Float16 hv = (_Float16)v;
        int base = (c * 19 + row) * 34;
        if (col >= 1)  xs[base + col - 1] = hv;        // P0
        if (col <= 33) xs[XPH + base + col] = hv;      // P1
    }
    __syncthreads();   // drains staging stores AND the chunk-kt0 prefetch

    // B-fragment base dword index into xs (per n-tile t = image row wave*2+t)
    const uint32_t* xsd = (const uint32_t*)xs;
    const int h = q >> 1;
    const int u = n15 + (n15 & 1) + ((q & 1) << 3);
    const int bdw0 = (n15 & 1) * (XPH / 2) + (u >> 1);
    int bdwt[2];
#pragma unroll
    for (int t = 0; t < 2; ++t)
        bdwt[t] = bdw0 + (wave * 2 + t + h) * 17;

    // ---------------- layer 1: 128ch x 576K x 32pix ----------------
    f32x4 acc1[2][8];
#pragma unroll
    for (int t = 0; t < 2; ++t)
#pragma unroll
        for (int mt = 0; mt < 8; ++mt)
            acc1[t][mt] = (f32x4){0.f, 0.f, 0.f, 0.f};

    int kt = kt0;
    for (int kk = 0; kk < NKT1; ++kk) {
        if (kk) __syncthreads();   // prev prefetch landed; cur buf safe to read
        const int buf  = kk & 1;
        const int nbuf = buf ^ 1;  // kk=17: buf=1, nbuf=0
        const int ktn  = (kt + 1 == NKT1) ? 0 : kt + 1;
        if (kk < NKT1 - 1) {       // prefetch next W1 chunk into other buffer
            int seg = wave * 2;
            async_cp16(w1p + ktn * 4096 + seg * 512 + lane * 8,
                       &w1s[nbuf * 4096 + seg * 512]);
            async_cp16(w1p + ktn * 4096 + (seg + 1) * 512 + lane * 8,
                       &w1s[nbuf * 4096 + (seg + 1) * 512]);
        } else {                   // last kt: stage W2 FIRST HALF (4 KB) only,
            int seg = wave * 2;    // strictly inside the idle nbuf half
#pragma unroll
            for (int s2 = 0; s2 < 2; ++s2)
                async_cp16(w2p + (seg + s2) * 512 + lane * 8,
                           &w1s[(seg + s2) * 512]);   // nbuf == 0
        }

        const int d6  = (kt >= 12) ? 2 : (kt >= 6 ? 1 : 0);
        const int m6  = kt - d6 * 6;
        const int rim = (d6 * 19 + 2 * m6) * 17;   // xs row offset (dwords)

        f16x8 bf[2];
#pragma unroll
        for (int t = 0; t < 2; ++t) {
            union { uint32_t u[4]; f16x8 f; } cv;
#pragma unroll
            for (int m = 0; m < 4; ++m)
                cv.u[m] = xsd[bdwt[t] + rim + m];
            bf[t] = cv.f;
        }
        const _Float16* wb = &w1s[buf * 4096];
#pragma unroll
        for (int mt = 0; mt < 8; ++mt) {
            f16x8 af = *(const f16x8*)(wb + (mt * 64 + lane) * 8);
            acc1[0][mt] = __builtin_amdgcn_mfma_f32_16x16x32_f16(af, bf[0], acc1[0][mt], 0, 0, 0);
            acc1[1][mt] = __builtin_amdgcn_mfma_f32_16x16x32_f16(af, bf[1], acc1[1][mt], 0, 0, 0);
        }
        kt = ktn;
    }
    __syncthreads();   // ALL waves done reading w1s[4096..8192) (chunk 17)

    // stage W2 SECOND HALF into w1s[4096..8192) (now dead)
    {
        int seg = wave * 2;
#pragma unroll
        for (int s2 = 0; s2 < 2; ++s2)
            async_cp16(w2p + 4096 + (seg + s2) * 512 + lane * 8,
                       &w1s[4096 + (seg + s2) * 512]);
    }
    __syncthreads();   // drain: w1s[0..8192) now holds packed W2

    const _Float16* w2s = w1s;
    _Float16* hw = hs[wave];             // wave-private 32-ch slice

    // ---------------- layer 2 (interleaved with epilogue 1) ----------------
    // per k2: stage h1 chs [k2*32, k2*32+32) from acc1 mt=2k2,2k2+1, then MFMA
    f32x4 acc2[2][4];
#pragma unroll
    for (int t = 0; t < 2; ++t)
#pragma unroll
        for (int mt = 0; mt < 4; ++mt)
            acc2[t][mt] = (f32x4){0.f, 0.f, 0.f, 0.f};

#pragma unroll
    for (int k2 = 0; k2 < 4; ++k2) {
#pragma unroll
        for (int lm = 0; lm < 2; ++lm) {
            int mt = 2 * k2 + lm;
            float4 bb = *(const float4*)(b1 + mt * 16 + q * 4);
#pragma unroll
            for (int t = 0; t < 2; ++t) {
                f16x4 hv;
#pragma unroll
                for (int r = 0; r < 4; ++r) {
                    float v = acc1[t][mt][r] + ((const float*)&bb)[r];
                    v = fmaxf(v, 0.01f * v);
                    hv[r] = (_Float16)v;
                }
                *(f16x4*)(hw + (t * 16 + n15) * HSS + lm * 16 + q * 4) = hv;
            }
        }
        // in-order DS per wave: reads below see this wave's writes above
        f16x8 bf[2];
#pragma unroll
        for (int t = 0; t < 2; ++t)
            bf[t] = *(const f16x8*)(hw + (t * 16 + n15) * HSS + q * 8);
#pragma unroll
        for (int mt2 = 0; mt2 < 4; ++mt2) {
            f16x8 af = *(const f16x8*)(w2s + ((k2 * 4 + mt2) * 64 + lane) * 8);
            acc2[0][mt2] = __builtin_amdgcn_mfma_f32_16x16x32_f16(af, bf[0], acc2[0][mt2], 0, 0, 0);
            acc2[1][mt2] = __builtin_amdgcn_mfma_f32_16x16x32_f16(af, bf[1], acc2[1][mt2], 0, 0, 0);
        }
    }

    // ---------------- layer 3 (interleaved with epilogue 2) ----------------
    f16x8 af3[2];
#pragma unroll
    for (int k3 = 0; k3 < 2; ++k3)
        af3[k3] = *(const f16x8*)(w3p + (k3 * 64 + lane) * 8);

    f32x4 acc3[2];
    acc3[0] = (f32x4){0.f, 0.f, 0.f, 0.f};
    acc3[1] = (f32x4){0.f, 0.f, 0.f, 0.f};
#pragma unroll
    for (int k3 = 0; k3 < 2; ++k3) {
#pragma unroll
        for (int lm = 0; lm < 2; ++lm) {
            int mt2 = 2 * k3 + lm;
            float4 bb = *(const float4*)(b2 + mt2 * 16 + q * 4);
#pragma unroll
            for (int t = 0; t < 2; ++t) {
                f16x4 hv;
#pragma unroll
                for (int r = 0; r < 4; ++r) {
                    float v = acc2[t][mt2][r] + ((const float*)&bb)[r];
                    v = fmaxf(v, 0.01f * v);
                    hv[r] = (_Float16)v;
                }
                *(f16x4*)(hw + (t * 16 + n15) * HSS + lm * 16 + q * 4) = hv;
            }
        }
#pragma unroll
        for (int t = 0; t < 2; ++t) {
            f16x8 bf = *(const f16x8*)(hw + (t * 16 + n15) * HSS + q * 8);
            acc3[t] = __builtin_amdgcn_mfma_f32_16x16x32_f16(af3[k3], bf, acc3[t], 0, 0, 0);
        }
    }

    // epilogue 3: +b3, L2-normalize over 8 ch (ch = q*4+r; q>=2 zero pad)
    float4 bb3 = make_float4(0.f, 0.f, 0.f, 0.f);
    if (q < 2) bb3 = *(const float4*)(b3 + q * 4);
#pragma unroll
    for (int t = 0; t < 2; ++t) {
        float v0 = acc3[t][0] + bb3.x;
        float v1 = acc3[t][1] + bb3.y;
        float v2 = acc3[t][2] + bb3.z;
        float v3 = acc3[t][3] + bb3.w;
        float s = v0 * v0 + v1 * v1 + v2 * v2 + v3 * v3;
        s += __shfl_xor(s, 16);
        s += __shfl_xor(s, 32);
        float inv = 1.0f / fmaxf(sqrtf(s), 1e-12f);
        if (q < 2) {
            int p = (by * 8 + wave * 2 + t) * IMG + bx * 16 + n15;
            float4 o = make_float4(v0 * inv, v1 * inv, v2 * inv, v3 * inv);
            *(float4*)(out + p * 8 + q * 4) = o;
        }
    }
}

extern "C" void kernel_launch(void* const* d_in, const int* in_sizes, int n_in,
                              void* d_out, int out_size, void* d_ws, size_t ws_size,
                              hipStream_t stream) {
    const float* x  = (const float*)d_in[0];
    const float* W1 = (const float*)d_in[1];
    const float* b1 = (const float*)d_in[2];
    const float* W2 = (const float*)d_in[3];
    const float* b2 = (const float*)d_in[4];
    const float* W3 = (const float*)d_in[5];
    const float* b3 = (const float*)d_in[6];
    float* out = (float*)d_out;
    _Float16* ws = (_Float16*)d_ws;   // needs 165888 B

    pack_weights<<<dim3(324), dim3(256), 0, stream>>>(W1, W2, W3, ws);
    fused_unfold_mlp<<<dim3(25, 50), dim3(256), 0, stream>>>(x, b1, b2, b3, ws, out);
}